// Round 3
// baseline (332.965 us; speedup 1.0000x reference)
//
#include <hip/hip_runtime.h>

#define N_VEC 131072   // B*H*W
#define DIM   64
#define KCODE 1024
#define HW    4096
#define DHW   262144
#define EPS   0.125f   // near-tie margin (validated r4-r8)
#define WLCAP 32768
#define BLK_ROWS 128   // rows per block; 4 waves x 32 rows
#define PITCH 72       // shorts per LDS row (144 B)
#define CPITCH 65      // rescue LDS pitch (odd -> conflict-free)
#define CHUNK_ROWS 256
#define RB_VEC 2       // rescue: vectors per wave
#define RB_BLK 8       // rescue: vectors per block (4 waves x 2)

typedef short short8 __attribute__((ext_vector_type(8)));
typedef float f32x4  __attribute__((ext_vector_type(4)));

// ws layout (bytes):
//   0      : double loss accumulator
//   8      : int flagged counter
//   12     : int done-ticket counter
//   64     : norms f32[1024]
//   8192   : eh  bf16-bits short[65536]
//   139264 : el  bf16-bits short[65536]
//   270336 : worklist int[WLCAP]

__device__ __forceinline__ unsigned short f32_to_bf16_rne(float x) {
    unsigned u = __float_as_uint(x);
    u += 0x7FFFu + ((u >> 16) & 1u);
    return (unsigned short)(u >> 16);
}
__device__ __forceinline__ float bf16_to_f32(unsigned short h) {
    return __uint_as_float((unsigned)h << 16);
}

__global__ __launch_bounds__(256) void vq_prep(
    const float* __restrict__ cb, float* __restrict__ norms,
    short* __restrict__ ehg, short* __restrict__ elg,
    double* __restrict__ loss_acc, int* __restrict__ counter,
    int* __restrict__ done)
{
    const int t = threadIdx.x;
    if (blockIdx.x == 0 && t == 0) { *loss_acc = 0.0; *counter = 0; *done = 0; }

    const int k    = blockIdx.x * 16 + (t >> 4);
    const int part = t & 15;
    const float4 v = *(const float4*)(cb + k * DIM + part * 4);

    float s = 0.f;
    s = fmaf(v.x, v.x, s); s = fmaf(v.y, v.y, s);
    s = fmaf(v.z, v.z, s); s = fmaf(v.w, v.w, s);
    #pragma unroll
    for (int m = 1; m <= 8; m <<= 1) s += __shfl_xor(s, m, 64);
    if (part == 0) norms[k] = s;

    short h[4], l[4];
    const float vv[4] = { v.x, v.y, v.z, v.w };
    #pragma unroll
    for (int j = 0; j < 4; ++j) {
        unsigned short hh = f32_to_bf16_rne(vv[j]);
        unsigned short ll = f32_to_bf16_rne(vv[j] - bf16_to_f32(hh));
        h[j] = (short)hh; l[j] = (short)ll;
    }
    *(short4*)(ehg + k * DIM + part * 4) = make_short4(h[0], h[1], h[2], h[3]);
    *(short4*)(elg + k * DIM + part * 4) = make_short4(l[0], l[1], l[2], l[3]);
}

// Main v4: no B-side LDS staging. The 256 KB packed codebook (ehg/elg) is
// chip-wide shared and L2-resident; each lane loads its MFMA B-fragments
// directly from global (16 B aligned short8) with a 1-deep prefetch of the
// next ct. K-loop is barrier-free (the only __syncthreads is the z-tile one),
// LDS drops to 37.4 KB -> 4 blocks/CU (was 2), and the 5.1M B-side LDS bank
// conflicts disappear. Top-2 VALU tracking unchanged.
__global__ __launch_bounds__(256, 4) void vq_main(
    const float* __restrict__ z, const float* __restrict__ cb,
    const float* __restrict__ norms, const short* __restrict__ ehg,
    const short* __restrict__ elg, float* __restrict__ out,
    double* __restrict__ loss_acc, int* __restrict__ counter,
    int* __restrict__ worklist, int cap)
{
    __shared__ short  zh[BLK_ROWS * PITCH];   // hi(-2z) bf16 bits, [row=hw][d]
    __shared__ short  zl[BLK_ROWS * PITCH];
    __shared__ int    kidx[BLK_ROWS];
    __shared__ float  wsum[4];

    const int t   = threadIdx.x;              // 0..255
    const int n0  = blockIdx.x * BLK_ROWS;
    const int b   = n0 >> 12;
    const int hw0 = n0 & 4095;

    const int lane = t & 63;
    const int wave = t >> 6;                  // 0..3
    const int l15  = lane & 15;
    const int quad = lane >> 4;
    const int rowbase = wave * 32;            // 2 row-tiles per wave

    // ---- stage z -> LDS (8 float4/thread, register transpose, b128 writes) ----
    {
        const int hwl   = (t & 31) * 4;       // 4 consecutive rows
        const int dbase = (t >> 5) * 8;       // 8 consecutive d
        float4 v[8];
        #pragma unroll
        for (int p = 0; p < 8; ++p)
            v[p] = *(const float4*)(z + (size_t)b * DHW + (size_t)(dbase + p) * HW + hw0 + hwl);
        #pragma unroll
        for (int c = 0; c < 4; ++c) {
            short8 hi, lo;
            #pragma unroll
            for (int p = 0; p < 8; ++p) {
                const float* vp = (const float*)&v[p];
                float f = -2.0f * vp[c];
                unsigned short hh = f32_to_bf16_rne(f);
                unsigned short ll = f32_to_bf16_rne(f - bf16_to_f32(hh));
                hi[p] = (short)hh; lo[p] = (short)ll;
            }
            *(short8*)&zh[(hwl + c) * PITCH + dbase] = hi;
            *(short8*)&zl[(hwl + c) * PITCH + dbase] = lo;
        }
    }
    __syncthreads();                          // z-tile ready (only block barrier)

    // ---- A-fragments (32 VGPRs, resident) ----
    short8 a_h[2][2], a_l[2][2];
    #pragma unroll
    for (int rt = 0; rt < 2; ++rt)
        #pragma unroll
        for (int kt = 0; kt < 2; ++kt) {
            const int idx = (rowbase + rt * 16 + l15) * PITCH + kt * 32 + quad * 8;
            a_h[rt][kt] = *(const short8*)&zh[idx];
            a_l[rt][kt] = *(const short8*)&zl[idx];
        }

    float best[2][4], best2[2][4];
    #pragma unroll
    for (int rt = 0; rt < 2; ++rt)
        #pragma unroll
        for (int r = 0; r < 4; ++r) { best[rt][r] = 3.0e38f; best2[rt][r] = 3.0e38f; }

    // ---- K-loop over all 1024 codes, B-fragments direct from global (L2) ----
    // Lane reads code row crow = ct*16 + l15; 1-deep prefetch. The ct=63
    // prefetch overruns ehg/elg by <4.2 KB but stays inside the workspace
    // (elg / worklist regions) -- safe, values never used.
    {
        int crow = l15;
        const size_t lo0 = (size_t)crow * DIM + (size_t)quad * 8;
        short8 Bh0 = *(const short8*)(ehg + lo0);
        short8 Bh1 = *(const short8*)(ehg + lo0 + 32);
        short8 Bl0 = *(const short8*)(elg + lo0);
        short8 Bl1 = *(const short8*)(elg + lo0 + 32);
        float  nrm = norms[crow];
        size_t boff = lo0;

        for (int ct = 0; ct < 64; ++ct) {
            const size_t nb = boff + (size_t)16 * DIM;
            short8 nBh0 = *(const short8*)(ehg + nb);
            short8 nBh1 = *(const short8*)(ehg + nb + 32);
            short8 nBl0 = *(const short8*)(elg + nb);
            short8 nBl1 = *(const short8*)(elg + nb + 32);
            float  nnrm = norms[crow + 16];

            const unsigned colbits = (unsigned)crow;
            #pragma unroll
            for (int rt = 0; rt < 2; ++rt) {
                f32x4 acc = { nrm, nrm, nrm, nrm };
                acc = __builtin_amdgcn_mfma_f32_16x16x32_bf16(a_h[rt][0], Bh0, acc, 0, 0, 0);
                acc = __builtin_amdgcn_mfma_f32_16x16x32_bf16(a_h[rt][1], Bh1, acc, 0, 0, 0);
                acc = __builtin_amdgcn_mfma_f32_16x16x32_bf16(a_h[rt][0], Bl0, acc, 0, 0, 0);
                acc = __builtin_amdgcn_mfma_f32_16x16x32_bf16(a_h[rt][1], Bl1, acc, 0, 0, 0);
                acc = __builtin_amdgcn_mfma_f32_16x16x32_bf16(a_l[rt][0], Bh0, acc, 0, 0, 0);
                acc = __builtin_amdgcn_mfma_f32_16x16x32_bf16(a_l[rt][1], Bh1, acc, 0, 0, 0);
                #pragma unroll
                for (int r = 0; r < 4; ++r) {
                    float p = __uint_as_float((__float_as_uint(acc[r]) & 0xFFFFFC00u) | colbits);
                    best2[rt][r] = fminf(best2[rt][r], fmaxf(best[rt][r], p));
                    best[rt][r]  = fminf(best[rt][r], p);
                }
            }

            Bh0 = nBh0; Bh1 = nBh1; Bl0 = nBl0; Bl1 = nBl1; nrm = nnrm;
            boff = nb; crow += 16;
        }
    }

    // ---- merge across 16 code-lanes; each wave has complete top-2 for its rows ----
    #pragma unroll
    for (int rt = 0; rt < 2; ++rt)
        #pragma unroll
        for (int r = 0; r < 4; ++r) {
            float bb = best[rt][r], b2 = best2[rt][r];
            #pragma unroll
            for (int m = 1; m <= 8; m <<= 1) {
                float ob  = __shfl_xor(bb, m, 64);
                float ob2 = __shfl_xor(b2, m, 64);
                b2 = fminf(fminf(b2, ob2), fmaxf(bb, ob));
                bb = fminf(bb, ob);
            }
            best[rt][r] = bb; best2[rt][r] = b2;
        }

    // ---- per-row result: index, flag, worklist (l15==0 lanes own one row each) ----
    if (l15 == 0) {
        #pragma unroll
        for (int rt = 0; rt < 2; ++rt)
            #pragma unroll
            for (int r = 0; r < 4; ++r) {
                unsigned ub = __float_as_uint(best[rt][r]);
                int k = (int)(ub & 1023u);
                float sb  = __uint_as_float(ub & 0xFFFFFC00u);
                float sb2 = __uint_as_float(__float_as_uint(best2[rt][r]) & 0xFFFFFC00u);
                int rowl = rt * 16 + quad * 4 + r;
                int flag = 0;
                if (sb2 - sb < EPS) {
                    int slot = atomicAdd(counter, 1);
                    if (slot < cap) { worklist[slot] = n0 + rowbase + rowl; flag = 1; }
                }
                kidx[rowbase + rowl] = k | (flag << 15);
            }
    }
    __syncthreads();

    // ---- epilogue: row = t&127, dgrp = t>>7 covers 32 d; coalesced stores ----
    float lsum = 0.f;
    {
        const int row  = t & 127;
        const int d0   = (t >> 7) * 32;
        const int ki   = kidx[row];
        const int k    = ki & 1023;
        const int flag = (ki >> 15) & 1;
        if (!flag) {
            const float4* cbr = (const float4*)(cb + k * DIM + d0);
            const short8* zhr = (const short8*)&zh[row * PITCH + d0];
            const short8* zlr = (const short8*)&zl[row * PITCH + d0];
            float* op = out + (size_t)b * DHW + (size_t)d0 * HW + hw0 + row;
            #pragma unroll
            for (int g = 0; g < 4; ++g) {
                short8 hh = zhr[g];
                short8 ll = zlr[g];
                float4 e0 = cbr[2 * g];
                float4 e1 = cbr[2 * g + 1];
                const float ev[8] = { e0.x, e0.y, e0.z, e0.w, e1.x, e1.y, e1.z, e1.w };
                #pragma unroll
                for (int j = 0; j < 8; ++j) {
                    float zv = -0.5f * (bf16_to_f32((unsigned short)hh[j]) +
                                        bf16_to_f32((unsigned short)ll[j]));
                    op[(size_t)(g * 8 + j) * HW] = ev[j];
                    float df = ev[j] - zv;
                    lsum = fmaf(df, df, lsum);
                }
            }
        }
    }
    #pragma unroll
    for (int off = 32; off > 0; off >>= 1) lsum += __shfl_down(lsum, off, 64);
    if (lane == 0) wsum[wave] = lsum;
    __syncthreads();
    if (t == 0)
        atomicAdd(loss_acc, (double)((wsum[0] + wsum[1]) + (wsum[2] + wsum[3])));
}

// Rescue v3: 8 flagged vectors per block (2 per wave), codebook staged once per
// block-iteration (4 chunks). f64 dot-form distance (||c||^2 - 2 z.c). Loss
// contributions block-reduced through LDS -> ONE f64 atomicAdd per
// block-iteration (fixed the per-vector same-address f64 RMW convoy).
__global__ __launch_bounds__(256, 2) void vq_rescue(
    const float* __restrict__ z, const float* __restrict__ cb,
    float* __restrict__ out, double* __restrict__ loss_acc,
    const int* __restrict__ counter, const int* __restrict__ worklist, int cap,
    int* __restrict__ done, float* __restrict__ loss_out)
{
    __shared__ float  cbs[CHUNK_ROWS * CPITCH];  // 66.5 KiB (one chunk)
    __shared__ float  zsh[RB_BLK][DIM];          // 2 KiB (per-wave private rows)
    __shared__ double dsum[4];

    int count = *counter; if (count > cap) count = cap;
    const int t    = threadIdx.x;
    const int wave = t >> 6;
    const int lane = t & 63;

    for (int base = blockIdx.x * RB_BLK; base < count; base += gridDim.x * RB_BLK) {
        int    nrow[RB_VEC];
        bool   act[RB_VEC];
        float  zval[RB_VEC];
        double znorm[RB_VEC];

        // issue all z-row loads up front (latency hides under chunk-0 staging)
        #pragma unroll
        for (int v = 0; v < RB_VEC; ++v) {
            const int i = base + wave * RB_VEC + v;
            act[v] = (i < count);
            nrow[v] = 0;
            zval[v] = 0.f;
            if (act[v]) {
                nrow[v] = worklist[i];
                const int bb = nrow[v] >> 12, hw = nrow[v] & 4095;
                zval[v] = z[(size_t)bb * DHW + (size_t)lane * HW + hw];
            }
        }
        #pragma unroll
        for (int v = 0; v < RB_VEC; ++v) {
            zsh[wave * RB_VEC + v][lane] = zval[v];
            double zn = (double)zval[v] * (double)zval[v];
            #pragma unroll
            for (int m = 1; m <= 32; m <<= 1) zn += __shfl_xor(zn, m, 64);
            znorm[v] = zn;
        }

        double bestd[RB_VEC]; int bestk[RB_VEC];
        #pragma unroll
        for (int v = 0; v < RB_VEC; ++v) { bestd[v] = 1.0e300; bestk[v] = 0; }

        for (int chunk = 0; chunk < 4; ++chunk) {
            __syncthreads();                 // previous chunk's readers done
            const float4* src = (const float4*)(cb + (size_t)chunk * CHUNK_ROWS * DIM);
            #pragma unroll
            for (int ii = 0; ii < 16; ++ii) {
                const int f = t + ii * 256;
                float4 v4 = src[f];
                float* dst = &cbs[(f >> 4) * CPITCH + (f & 15) * 4];
                dst[0] = v4.x; dst[1] = v4.y; dst[2] = v4.z; dst[3] = v4.w;
            }
            __syncthreads();                 // chunk visible

            double nj[4];                    // ||c_row||^2, f64, per j
            double dot[4][RB_VEC];           // z.c per (row, vector)
            #pragma unroll
            for (int j = 0; j < 4; ++j) {
                nj[j] = 0.0;
                #pragma unroll
                for (int v = 0; v < RB_VEC; ++v) dot[j][v] = 0.0;
            }
            #pragma unroll
            for (int dblk = 0; dblk < 8; ++dblk) {
                float zb[RB_VEC][8];
                #pragma unroll
                for (int v = 0; v < RB_VEC; ++v)
                    #pragma unroll
                    for (int dd = 0; dd < 8; ++dd)
                        zb[v][dd] = zsh[wave * RB_VEC + v][dblk * 8 + dd];
                #pragma unroll
                for (int j = 0; j < 4; ++j) {
                    const float* cr = &cbs[(j * 64 + lane) * CPITCH + dblk * 8];
                    float cv[8];
                    #pragma unroll
                    for (int dd = 0; dd < 8; ++dd) cv[dd] = cr[dd];
                    #pragma unroll
                    for (int dd = 0; dd < 8; ++dd)
                        nj[j] = fma((double)cv[dd], (double)cv[dd], nj[j]);
                    #pragma unroll
                    for (int v = 0; v < RB_VEC; ++v)
                        #pragma unroll
                        for (int dd = 0; dd < 8; ++dd)
                            dot[j][v] = fma((double)cv[dd], (double)zb[v][dd], dot[j][v]);
                }
            }
            #pragma unroll
            for (int j = 0; j < 4; ++j) {
                const int gk = chunk * CHUNK_ROWS + j * 64 + lane;
                #pragma unroll
                for (int v = 0; v < RB_VEC; ++v) {
                    double d2 = fma(-2.0, dot[j][v], nj[j]);   // ||c||^2 - 2 z.c
                    if (d2 < bestd[v]) { bestd[v] = d2; bestk[v] = gk; }
                }
            }
        }

        double lloss = 0.0;                  // lane0-of-wave partial loss
        #pragma unroll
        for (int v = 0; v < RB_VEC; ++v) {
            double bd = bestd[v]; int bk = bestk[v];
            #pragma unroll
            for (int m = 1; m <= 32; m <<= 1) {
                double od = __shfl_xor(bd, m, 64);
                int    ok = __shfl_xor(bk, m, 64);
                if (od < bd || (od == bd && ok < bk)) { bd = od; bk = ok; }
            }
            if (act[v]) {
                const int bb = nrow[v] >> 12, hw = nrow[v] & 4095;
                out[(size_t)bb * DHW + (size_t)lane * HW + hw] = cb[bk * DIM + lane];
                if (lane == 0) lloss += bd + znorm[v];
            }
        }
        // block-reduce loss -> single f64 atomic per block-iteration
        if (lane == 0) dsum[wave] = lloss;
        __syncthreads();
        if (t == 0) {
            double s = (dsum[0] + dsum[1]) + (dsum[2] + dsum[3]);
            if (s != 0.0) atomicAdd(loss_acc, s);
        }
    }

    __threadfence();
    __shared__ int ticket_s;
    if (t == 0) ticket_s = atomicAdd(done, 1);
    __syncthreads();
    if (t == 0 && ticket_s == (int)gridDim.x - 1) {
        double total = atomicAdd(loss_acc, 0.0);
        *loss_out = (float)(1.25 * total * (1.0 / (double)((long)N_VEC * DIM)));
    }
}

extern "C" void kernel_launch(void* const* d_in, const int* in_sizes, int n_in,
                              void* d_out, int out_size, void* d_ws, size_t ws_size,
                              hipStream_t stream) {
    const float* z  = (const float*)d_in[0];
    const float* cb = (const float*)d_in[1];
    float* out      = (float*)d_out;
    char*  ws       = (char*)d_ws;

    double* loss_acc = (double*)ws;
    int*    counter  = (int*)(ws + 8);
    int*    done     = (int*)(ws + 12);
    float*  norms    = (float*)(ws + 64);
    short*  ehg      = (short*)(ws + 8192);
    short*  elg      = (short*)(ws + 139264);
    int*    worklist = (int*)(ws + 270336);

    int cap = WLCAP;
    long avail = ((long)ws_size - 270336) / 4;
    if (avail < cap) cap = (avail > 0) ? (int)avail : 0;

    vq_prep<<<dim3(KCODE / 16), dim3(256), 0, stream>>>(
        cb, norms, ehg, elg, loss_acc, counter, done);
    vq_main<<<dim3(N_VEC / BLK_ROWS), dim3(256), 0, stream>>>(
        z, cb, norms, ehg, elg, out, loss_acc, counter, worklist, cap);
    vq_rescue<<<dim3(512), dim3(256), 0, stream>>>(
        z, cb, out, loss_acc, counter, worklist, cap, done, out + (out_size - 1));
}

// Round 4
// 262.665 us; speedup vs baseline: 1.2676x; 1.2676x over previous
//
#include <hip/hip_runtime.h>

#define N_VEC 131072   // B*H*W
#define DIM   64
#define KCODE 1024
#define HW    4096
#define DHW   262144
#define EPS   0.125f   // near-tie margin (validated r4-r8)
#define WLCAP 32768
#define BLK_ROWS 128   // rows per block; 4 waves x 32 rows
#define PITCH 72       // shorts per LDS row (144 B)
#define BCHUNK 64      // main: codes per LDS-staged codebook chunk
#define NBCHUNK 16
#define CPITCH 65      // rescue LDS pitch (odd -> conflict-free)
#define CHUNK_ROWS 256
#define RB_VEC 2       // rescue: vectors per wave
#define RB_BLK 8       // rescue: vectors per block (4 waves x 2)

typedef short short8 __attribute__((ext_vector_type(8)));
typedef float f32x4  __attribute__((ext_vector_type(4)));

// ws layout (bytes):
//   0      : double loss accumulator
//   8      : int flagged counter
//   12     : int done-ticket counter
//   64     : norms f32[1024]
//   8192   : eh  bf16-bits short[65536]
//   139264 : el  bf16-bits short[65536]
//   270336 : worklist int[WLCAP]

__device__ __forceinline__ unsigned short f32_to_bf16_rne(float x) {
    unsigned u = __float_as_uint(x);
    u += 0x7FFFu + ((u >> 16) & 1u);
    return (unsigned short)(u >> 16);
}
__device__ __forceinline__ float bf16_to_f32(unsigned short h) {
    return __uint_as_float((unsigned)h << 16);
}

__global__ __launch_bounds__(256) void vq_prep(
    const float* __restrict__ cb, float* __restrict__ norms,
    short* __restrict__ ehg, short* __restrict__ elg,
    double* __restrict__ loss_acc, int* __restrict__ counter,
    int* __restrict__ done)
{
    const int t = threadIdx.x;
    if (blockIdx.x == 0 && t == 0) { *loss_acc = 0.0; *counter = 0; *done = 0; }

    const int k    = blockIdx.x * 16 + (t >> 4);
    const int part = t & 15;
    const float4 v = *(const float4*)(cb + k * DIM + part * 4);

    float s = 0.f;
    s = fmaf(v.x, v.x, s); s = fmaf(v.y, v.y, s);
    s = fmaf(v.z, v.z, s); s = fmaf(v.w, v.w, s);
    #pragma unroll
    for (int m = 1; m <= 8; m <<= 1) s += __shfl_xor(s, m, 64);
    if (part == 0) norms[k] = s;

    short h[4], l[4];
    const float vv[4] = { v.x, v.y, v.z, v.w };
    #pragma unroll
    for (int j = 0; j < 4; ++j) {
        unsigned short hh = f32_to_bf16_rne(vv[j]);
        unsigned short ll = f32_to_bf16_rne(vv[j] - bf16_to_f32(hh));
        h[j] = (short)hh; l[j] = (short)ll;
    }
    *(short4*)(ehg + k * DIM + part * 4) = make_short4(h[0], h[1], h[2], h[3]);
    *(short4*)(elg + k * DIM + part * 4) = make_short4(l[0], l[1], l[2], l[3]);
}

// Main v5: LDS-staged B (R2 structure) with the barrier stall fixed.
// - B chunk double-buffered (64 codes/chunk): ONE barrier per chunk, and the
//   chunk ch+2 global loads are issued at the TOP of chunk ch's body, so they
//   have a full compute phase (~4 ct of MFMA+VALU) in flight before the
//   compiler's vmcnt(0)-at-barrier drain -- the drain that serialized R2.
// - Named register sets pf0/pf1 + hand-two-phased loop (lambda with
//   compile-time buffer pointers): no runtime-indexed register arrays, no
//   compiler-defeatable rotation (R3's failure: VGPR=52 proved the reg
//   double-buffer was collapsed and loads sank to use points).
// - norms staged to LDS once per block; per-chunk norm reads hoisted ahead
//   of the MFMA chain they gate.
__global__ __launch_bounds__(256, 2) void vq_main(
    const float* __restrict__ z, const float* __restrict__ cb,
    const float* __restrict__ norms, const short* __restrict__ ehg,
    const short* __restrict__ elg, float* __restrict__ out,
    double* __restrict__ loss_acc, int* __restrict__ counter,
    int* __restrict__ worklist, int cap)
{
    __shared__ short  zh[BLK_ROWS * PITCH];   // hi(-2z) bf16 bits, [row=hw][d]
    __shared__ short  zl[BLK_ROWS * PITCH];
    __shared__ short  ebh0[BCHUNK * PITCH];   // codebook chunk hi, double-buffered
    __shared__ short  ebh1[BCHUNK * PITCH];
    __shared__ short  ebl0[BCHUNK * PITCH];
    __shared__ short  ebl1[BCHUNK * PITCH];
    __shared__ float  nsh[KCODE];             // norms, block-resident
    __shared__ int    kidx[BLK_ROWS];
    __shared__ float  wsum[4];

    const int t   = threadIdx.x;              // 0..255
    const int n0  = blockIdx.x * BLK_ROWS;
    const int b   = n0 >> 12;
    const int hw0 = n0 & 4095;

    const int lane = t & 63;
    const int wave = t >> 6;                  // 0..3
    const int l15  = lane & 15;
    const int quad = lane >> 4;
    const int rowbase = wave * 32;            // 2 row-tiles per wave

    // ---- stage z -> LDS (8 float4/thread, register transpose, b128 writes) ----
    {
        const int hwl   = (t & 31) * 4;       // 4 consecutive rows
        const int dbase = (t >> 5) * 8;       // 8 consecutive d
        float4 v[8];
        #pragma unroll
        for (int p = 0; p < 8; ++p)
            v[p] = *(const float4*)(z + (size_t)b * DHW + (size_t)(dbase + p) * HW + hw0 + hwl);
        #pragma unroll
        for (int c = 0; c < 4; ++c) {
            short8 hi, lo;
            #pragma unroll
            for (int p = 0; p < 8; ++p) {
                const float* vp = (const float*)&v[p];
                float f = -2.0f * vp[c];
                unsigned short hh = f32_to_bf16_rne(f);
                unsigned short ll = f32_to_bf16_rne(f - bf16_to_f32(hh));
                hi[p] = (short)hh; lo[p] = (short)ll;
            }
            *(short8*)&zh[(hwl + c) * PITCH + dbase] = hi;
            *(short8*)&zl[(hwl + c) * PITCH + dbase] = lo;
        }
    }

    // ---- stage norms -> LDS ----
    #pragma unroll
    for (int j = 0; j < 4; ++j) nsh[t + j * 256] = norms[t + j * 256];

    // ---- B-staging prologue: thread owns 32 B hi + 32 B lo per chunk ----
    const int cc = t >> 2;                    // code within chunk (0..63)
    const int pp = (t & 3) * 16;              // short offset within code row
    short8 pf0[4], pf1[4];                    // [0..1]=hi, [2..3]=lo
    #pragma unroll
    for (int j = 0; j < 2; ++j) {
        pf0[j]     = *(const short8*)(ehg + (size_t)cc * DIM + pp + j * 8);
        pf0[2 + j] = *(const short8*)(elg + (size_t)cc * DIM + pp + j * 8);
        pf1[j]     = *(const short8*)(ehg + (size_t)(BCHUNK + cc) * DIM + pp + j * 8);
        pf1[2 + j] = *(const short8*)(elg + (size_t)(BCHUNK + cc) * DIM + pp + j * 8);
    }
    __syncthreads();                          // z + norms ready (prologue loads drain once)

    // ---- A-fragments (32 VGPRs, resident) ----
    short8 a_h[2][2], a_l[2][2];
    #pragma unroll
    for (int rt = 0; rt < 2; ++rt)
        #pragma unroll
        for (int kt = 0; kt < 2; ++kt) {
            const int idx = (rowbase + rt * 16 + l15) * PITCH + kt * 32 + quad * 8;
            a_h[rt][kt] = *(const short8*)&zh[idx];
            a_l[rt][kt] = *(const short8*)&zl[idx];
        }

    // ---- write chunk 0 into buf0 ----
    #pragma unroll
    for (int j = 0; j < 2; ++j) {
        *(short8*)&ebh0[cc * PITCH + pp + j * 8] = pf0[j];
        *(short8*)&ebl0[cc * PITCH + pp + j * 8] = pf0[2 + j];
    }
    __syncthreads();                          // buf0 ready

    float best[2][4], best2[2][4];
    #pragma unroll
    for (int rt = 0; rt < 2; ++rt)
        #pragma unroll
        for (int r = 0; r < 4; ++r) { best[rt][r] = 3.0e38f; best2[rt][r] = 3.0e38f; }

    // chunk body: issue ch+2 loads -> pfL; compute chunk ch from (bhR,blR);
    // write pfW (chunk ch+1) -> (bhW,blW); barrier.
    auto body = [&](int ch, const short* bhR, const short* blR,
                    short* bhW, short* blW, short8 (&pfL)[4], short8 (&pfW)[4]) {
        if (ch + 2 < NBCHUNK) {
            const size_t gb = (size_t)((ch + 2) * BCHUNK + cc) * DIM + pp;
            #pragma unroll
            for (int j = 0; j < 2; ++j) {
                pfL[j]     = *(const short8*)(ehg + gb + j * 8);
                pfL[2 + j] = *(const short8*)(elg + gb + j * 8);
            }
        }
        // hoist the 4 norm reads (they gate each MFMA chain's acc init)
        float nrm4[4];
        #pragma unroll
        for (int ct = 0; ct < 4; ++ct) nrm4[ct] = nsh[ch * BCHUNK + ct * 16 + l15];

        #pragma unroll
        for (int ct = 0; ct < 4; ++ct) {
            const int crow = ct * 16 + l15;
            short8 Bh0 = *(const short8*)&bhR[crow * PITCH + quad * 8];
            short8 Bh1 = *(const short8*)&bhR[crow * PITCH + 32 + quad * 8];
            short8 Bl0 = *(const short8*)&blR[crow * PITCH + quad * 8];
            short8 Bl1 = *(const short8*)&blR[crow * PITCH + 32 + quad * 8];
            const unsigned colbits = (unsigned)(ch * BCHUNK + crow);
            const float nrm = nrm4[ct];
            #pragma unroll
            for (int rt = 0; rt < 2; ++rt) {
                f32x4 acc = { nrm, nrm, nrm, nrm };
                acc = __builtin_amdgcn_mfma_f32_16x16x32_bf16(a_h[rt][0], Bh0, acc, 0, 0, 0);
                acc = __builtin_amdgcn_mfma_f32_16x16x32_bf16(a_h[rt][1], Bh1, acc, 0, 0, 0);
                acc = __builtin_amdgcn_mfma_f32_16x16x32_bf16(a_h[rt][0], Bl0, acc, 0, 0, 0);
                acc = __builtin_amdgcn_mfma_f32_16x16x32_bf16(a_h[rt][1], Bl1, acc, 0, 0, 0);
                acc = __builtin_amdgcn_mfma_f32_16x16x32_bf16(a_l[rt][0], Bh0, acc, 0, 0, 0);
                acc = __builtin_amdgcn_mfma_f32_16x16x32_bf16(a_l[rt][1], Bh1, acc, 0, 0, 0);
                #pragma unroll
                for (int r = 0; r < 4; ++r) {
                    float p = __uint_as_float((__float_as_uint(acc[r]) & 0xFFFFFC00u) | colbits);
                    best2[rt][r] = fminf(best2[rt][r], fmaxf(best[rt][r], p));
                    best[rt][r]  = fminf(best[rt][r], p);
                }
            }
        }
        if (ch + 1 < NBCHUNK) {
            #pragma unroll
            for (int j = 0; j < 2; ++j) {
                *(short8*)&bhW[cc * PITCH + pp + j * 8] = pfW[j];
                *(short8*)&blW[cc * PITCH + pp + j * 8] = pfW[2 + j];
            }
        }
        __syncthreads();
    };

    for (int chp = 0; chp < 8; ++chp) {
        body(2 * chp,     ebh0, ebl0, ebh1, ebl1, pf0, pf1);
        body(2 * chp + 1, ebh1, ebl1, ebh0, ebl0, pf1, pf0);
    }

    // ---- merge across 16 code-lanes; each wave has complete top-2 for its rows ----
    #pragma unroll
    for (int rt = 0; rt < 2; ++rt)
        #pragma unroll
        for (int r = 0; r < 4; ++r) {
            float bb = best[rt][r], b2 = best2[rt][r];
            #pragma unroll
            for (int m = 1; m <= 8; m <<= 1) {
                float ob  = __shfl_xor(bb, m, 64);
                float ob2 = __shfl_xor(b2, m, 64);
                b2 = fminf(fminf(b2, ob2), fmaxf(bb, ob));
                bb = fminf(bb, ob);
            }
            best[rt][r] = bb; best2[rt][r] = b2;
        }

    // ---- per-row result: index, flag, worklist (l15==0 lanes own one row each) ----
    if (l15 == 0) {
        #pragma unroll
        for (int rt = 0; rt < 2; ++rt)
            #pragma unroll
            for (int r = 0; r < 4; ++r) {
                unsigned ub = __float_as_uint(best[rt][r]);
                int k = (int)(ub & 1023u);
                float sb  = __uint_as_float(ub & 0xFFFFFC00u);
                float sb2 = __uint_as_float(__float_as_uint(best2[rt][r]) & 0xFFFFFC00u);
                int rowl = rt * 16 + quad * 4 + r;
                int flag = 0;
                if (sb2 - sb < EPS) {
                    int slot = atomicAdd(counter, 1);
                    if (slot < cap) { worklist[slot] = n0 + rowbase + rowl; flag = 1; }
                }
                kidx[rowbase + rowl] = k | (flag << 15);
            }
    }
    __syncthreads();

    // ---- epilogue: row = t&127, dgrp = t>>7 covers 32 d; coalesced stores ----
    float lsum = 0.f;
    {
        const int row  = t & 127;
        const int d0   = (t >> 7) * 32;
        const int ki   = kidx[row];
        const int k    = ki & 1023;
        const int flag = (ki >> 15) & 1;
        if (!flag) {
            const float4* cbr = (const float4*)(cb + k * DIM + d0);
            const short8* zhr = (const short8*)&zh[row * PITCH + d0];
            const short8* zlr = (const short8*)&zl[row * PITCH + d0];
            float* op = out + (size_t)b * DHW + (size_t)d0 * HW + hw0 + row;
            #pragma unroll
            for (int g = 0; g < 4; ++g) {
                short8 hh = zhr[g];
                short8 ll = zlr[g];
                float4 e0 = cbr[2 * g];
                float4 e1 = cbr[2 * g + 1];
                const float ev[8] = { e0.x, e0.y, e0.z, e0.w, e1.x, e1.y, e1.z, e1.w };
                #pragma unroll
                for (int j = 0; j < 8; ++j) {
                    float zv = -0.5f * (bf16_to_f32((unsigned short)hh[j]) +
                                        bf16_to_f32((unsigned short)ll[j]));
                    op[(size_t)(g * 8 + j) * HW] = ev[j];
                    float df = ev[j] - zv;
                    lsum = fmaf(df, df, lsum);
                }
            }
        }
    }
    #pragma unroll
    for (int off = 32; off > 0; off >>= 1) lsum += __shfl_down(lsum, off, 64);
    if (lane == 0) wsum[wave] = lsum;
    __syncthreads();
    if (t == 0)
        atomicAdd(loss_acc, (double)((wsum[0] + wsum[1]) + (wsum[2] + wsum[3])));
}

// Rescue v3: 8 flagged vectors per block (2 per wave), codebook staged once per
// block-iteration (4 chunks). f64 dot-form distance (||c||^2 - 2 z.c). Loss
// contributions block-reduced through LDS -> ONE f64 atomicAdd per
// block-iteration (fixed the per-vector same-address f64 RMW convoy).
__global__ __launch_bounds__(256, 2) void vq_rescue(
    const float* __restrict__ z, const float* __restrict__ cb,
    float* __restrict__ out, double* __restrict__ loss_acc,
    const int* __restrict__ counter, const int* __restrict__ worklist, int cap,
    int* __restrict__ done, float* __restrict__ loss_out)
{
    __shared__ float  cbs[CHUNK_ROWS * CPITCH];  // 66.5 KiB (one chunk)
    __shared__ float  zsh[RB_BLK][DIM];          // 2 KiB (per-wave private rows)
    __shared__ double dsum[4];

    int count = *counter; if (count > cap) count = cap;
    const int t    = threadIdx.x;
    const int wave = t >> 6;
    const int lane = t & 63;

    for (int base = blockIdx.x * RB_BLK; base < count; base += gridDim.x * RB_BLK) {
        int    nrow[RB_VEC];
        bool   act[RB_VEC];
        float  zval[RB_VEC];
        double znorm[RB_VEC];

        // issue all z-row loads up front (latency hides under chunk-0 staging)
        #pragma unroll
        for (int v = 0; v < RB_VEC; ++v) {
            const int i = base + wave * RB_VEC + v;
            act[v] = (i < count);
            nrow[v] = 0;
            zval[v] = 0.f;
            if (act[v]) {
                nrow[v] = worklist[i];
                const int bb = nrow[v] >> 12, hw = nrow[v] & 4095;
                zval[v] = z[(size_t)bb * DHW + (size_t)lane * HW + hw];
            }
        }
        #pragma unroll
        for (int v = 0; v < RB_VEC; ++v) {
            zsh[wave * RB_VEC + v][lane] = zval[v];
            double zn = (double)zval[v] * (double)zval[v];
            #pragma unroll
            for (int m = 1; m <= 32; m <<= 1) zn += __shfl_xor(zn, m, 64);
            znorm[v] = zn;
        }

        double bestd[RB_VEC]; int bestk[RB_VEC];
        #pragma unroll
        for (int v = 0; v < RB_VEC; ++v) { bestd[v] = 1.0e300; bestk[v] = 0; }

        for (int chunk = 0; chunk < 4; ++chunk) {
            __syncthreads();                 // previous chunk's readers done
            const float4* src = (const float4*)(cb + (size_t)chunk * CHUNK_ROWS * DIM);
            #pragma unroll
            for (int ii = 0; ii < 16; ++ii) {
                const int f = t + ii * 256;
                float4 v4 = src[f];
                float* dst = &cbs[(f >> 4) * CPITCH + (f & 15) * 4];
                dst[0] = v4.x; dst[1] = v4.y; dst[2] = v4.z; dst[3] = v4.w;
            }
            __syncthreads();                 // chunk visible

            double nj[4];                    // ||c_row||^2, f64, per j
            double dot[4][RB_VEC];           // z.c per (row, vector)
            #pragma unroll
            for (int j = 0; j < 4; ++j) {
                nj[j] = 0.0;
                #pragma unroll
                for (int v = 0; v < RB_VEC; ++v) dot[j][v] = 0.0;
            }
            #pragma unroll
            for (int dblk = 0; dblk < 8; ++dblk) {
                float zb[RB_VEC][8];
                #pragma unroll
                for (int v = 0; v < RB_VEC; ++v)
                    #pragma unroll
                    for (int dd = 0; dd < 8; ++dd)
                        zb[v][dd] = zsh[wave * RB_VEC + v][dblk * 8 + dd];
                #pragma unroll
                for (int j = 0; j < 4; ++j) {
                    const float* cr = &cbs[(j * 64 + lane) * CPITCH + dblk * 8];
                    float cv[8];
                    #pragma unroll
                    for (int dd = 0; dd < 8; ++dd) cv[dd] = cr[dd];
                    #pragma unroll
                    for (int dd = 0; dd < 8; ++dd)
                        nj[j] = fma((double)cv[dd], (double)cv[dd], nj[j]);
                    #pragma unroll
                    for (int v = 0; v < RB_VEC; ++v)
                        #pragma unroll
                        for (int dd = 0; dd < 8; ++dd)
                            dot[j][v] = fma((double)cv[dd], (double)zb[v][dd], dot[j][v]);
                }
            }
            #pragma unroll
            for (int j = 0; j < 4; ++j) {
                const int gk = chunk * CHUNK_ROWS + j * 64 + lane;
                #pragma unroll
                for (int v = 0; v < RB_VEC; ++v) {
                    double d2 = fma(-2.0, dot[j][v], nj[j]);   // ||c||^2 - 2 z.c
                    if (d2 < bestd[v]) { bestd[v] = d2; bestk[v] = gk; }
                }
            }
        }

        double lloss = 0.0;                  // lane0-of-wave partial loss
        #pragma unroll
        for (int v = 0; v < RB_VEC; ++v) {
            double bd = bestd[v]; int bk = bestk[v];
            #pragma unroll
            for (int m = 1; m <= 32; m <<= 1) {
                double od = __shfl_xor(bd, m, 64);
                int    ok = __shfl_xor(bk, m, 64);
                if (od < bd || (od == bd && ok < bk)) { bd = od; bk = ok; }
            }
            if (act[v]) {
                const int bb = nrow[v] >> 12, hw = nrow[v] & 4095;
                out[(size_t)bb * DHW + (size_t)lane * HW + hw] = cb[bk * DIM + lane];
                if (lane == 0) lloss += bd + znorm[v];
            }
        }
        // block-reduce loss -> single f64 atomic per block-iteration
        if (lane == 0) dsum[wave] = lloss;
        __syncthreads();
        if (t == 0) {
            double s = (dsum[0] + dsum[1]) + (dsum[2] + dsum[3]);
            if (s != 0.0) atomicAdd(loss_acc, s);
        }
    }

    __threadfence();
    __shared__ int ticket_s;
    if (t == 0) ticket_s = atomicAdd(done, 1);
    __syncthreads();
    if (t == 0 && ticket_s == (int)gridDim.x - 1) {
        double total = atomicAdd(loss_acc, 0.0);
        *loss_out = (float)(1.25 * total * (1.0 / (double)((long)N_VEC * DIM)));
    }
}

extern "C" void kernel_launch(void* const* d_in, const int* in_sizes, int n_in,
                              void* d_out, int out_size, void* d_ws, size_t ws_size,
                              hipStream_t stream) {
    const float* z  = (const float*)d_in[0];
    const float* cb = (const float*)d_in[1];
    float* out      = (float*)d_out;
    char*  ws       = (char*)d_ws;

    double* loss_acc = (double*)ws;
    int*    counter  = (int*)(ws + 8);
    int*    done     = (int*)(ws + 12);
    float*  norms    = (float*)(ws + 64);
    short*  ehg      = (short*)(ws + 8192);
    short*  elg      = (short*)(ws + 139264);
    int*    worklist = (int*)(ws + 270336);

    int cap = WLCAP;
    long avail = ((long)ws_size - 270336) / 4;
    if (avail < cap) cap = (avail > 0) ? (int)avail : 0;

    vq_prep<<<dim3(KCODE / 16), dim3(256), 0, stream>>>(
        cb, norms, ehg, elg, loss_acc, counter, done);
    vq_main<<<dim3(N_VEC / BLK_ROWS), dim3(256), 0, stream>>>(
        z, cb, norms, ehg, elg, out, loss_acc, counter, worklist, cap);
    vq_rescue<<<dim3(512), dim3(256), 0, stream>>>(
        z, cb, out, loss_acc, counter, worklist, cap, done, out + (out_size - 1));
}

// Round 5
// 230.392 us; speedup vs baseline: 1.4452x; 1.1401x over previous
//
#include <hip/hip_runtime.h>

#define N_VEC 131072   // B*H*W
#define DIM   64
#define KCODE 1024
#define HW    4096
#define DHW   262144
#define EPS   0.125f   // near-tie margin (validated r4-r8)
#define WLCAP 32768
#define BLK_ROWS 128   // rows per block; 4 waves x 32 rows
#define PITCH 72       // shorts per LDS row (144 B)
#define BCHUNK 64      // main: codes per LDS-staged codebook chunk
#define NBCHUNK 16
#define CPITCH 65      // rescue LDS pitch (odd -> conflict-free)
#define CHUNK_ROWS 256
#define RB_VEC 2       // rescue: vectors per wave
#define RB_BLK 8       // rescue: vectors per block (4 waves x 2)

typedef short short8 __attribute__((ext_vector_type(8)));
typedef float f32x4  __attribute__((ext_vector_type(4)));

// ws layout (bytes):
//   0      : double loss accumulator
//   8      : int flagged counter
//   12     : int done-ticket counter
//   64     : norms f32[1024]
//   8192   : eh  bf16-bits short[65536]
//   139264 : el  bf16-bits short[65536]
//   270336 : worklist int[WLCAP]

__device__ __forceinline__ unsigned short f32_to_bf16_rne(float x) {
    unsigned u = __float_as_uint(x);
    u += 0x7FFFu + ((u >> 16) & 1u);
    return (unsigned short)(u >> 16);
}
__device__ __forceinline__ float bf16_to_f32(unsigned short h) {
    return __uint_as_float((unsigned)h << 16);
}

__global__ __launch_bounds__(256) void vq_prep(
    const float* __restrict__ cb, float* __restrict__ norms,
    short* __restrict__ ehg, short* __restrict__ elg,
    double* __restrict__ loss_acc, int* __restrict__ counter,
    int* __restrict__ done)
{
    const int t = threadIdx.x;
    if (blockIdx.x == 0 && t == 0) { *loss_acc = 0.0; *counter = 0; *done = 0; }

    const int k    = blockIdx.x * 16 + (t >> 4);
    const int part = t & 15;
    const float4 v = *(const float4*)(cb + k * DIM + part * 4);

    float s = 0.f;
    s = fmaf(v.x, v.x, s); s = fmaf(v.y, v.y, s);
    s = fmaf(v.z, v.z, s); s = fmaf(v.w, v.w, s);
    #pragma unroll
    for (int m = 1; m <= 8; m <<= 1) s += __shfl_xor(s, m, 64);
    if (part == 0) norms[k] = s;

    short h[4], l[4];
    const float vv[4] = { v.x, v.y, v.z, v.w };
    #pragma unroll
    for (int j = 0; j < 4; ++j) {
        unsigned short hh = f32_to_bf16_rne(vv[j]);
        unsigned short ll = f32_to_bf16_rne(vv[j] - bf16_to_f32(hh));
        h[j] = (short)hh; l[j] = (short)ll;
    }
    *(short4*)(ehg + k * DIM + part * 4) = make_short4(h[0], h[1], h[2], h[3]);
    *(short4*)(elg + k * DIM + part * 4) = make_short4(l[0], l[1], l[2], l[3]);
}

// Main v6 = v5 structure + the worklist-slot fix. The schedule-invariant
// ~112 us across R2/R4 (identical counters both rounds) matches the ~3700
// same-address atomicAdd(counter,1)-with-return convoy (~30 ns each
// serialized at the coherence point -- same signature as the R0/R1 rescue
// loss-atomic convoy at ~112 us). Fix: per-block LDS aggregation -- flagged
// rows collected via LDS atomics, ONE global atomicAdd per block reserves a
// contiguous slot range (1024 atomics instead of ~3700, and no wave stalls
// on a per-row RMW return); overflow slots (>= cap) get their flag cleared
// before the epilogue reads kidx (identical semantics).
__global__ __launch_bounds__(256, 2) void vq_main(
    const float* __restrict__ z, const float* __restrict__ cb,
    const float* __restrict__ norms, const short* __restrict__ ehg,
    const short* __restrict__ elg, float* __restrict__ out,
    double* __restrict__ loss_acc, int* __restrict__ counter,
    int* __restrict__ worklist, int cap)
{
    __shared__ short  zh[BLK_ROWS * PITCH];   // hi(-2z) bf16 bits, [row=hw][d]
    __shared__ short  zl[BLK_ROWS * PITCH];
    __shared__ short  ebh0[BCHUNK * PITCH];   // codebook chunk hi, double-buffered
    __shared__ short  ebh1[BCHUNK * PITCH];
    __shared__ short  ebl0[BCHUNK * PITCH];
    __shared__ short  ebl1[BCHUNK * PITCH];
    __shared__ float  nsh[KCODE];             // norms, block-resident
    __shared__ int    kidx[BLK_ROWS];
    __shared__ float  wsum[4];
    __shared__ int    blkrows[BLK_ROWS];      // flagged row-local ids
    __shared__ int    blkcnt;
    __shared__ int    blkbase;

    const int t   = threadIdx.x;              // 0..255
    const int n0  = blockIdx.x * BLK_ROWS;
    const int b   = n0 >> 12;
    const int hw0 = n0 & 4095;

    const int lane = t & 63;
    const int wave = t >> 6;                  // 0..3
    const int l15  = lane & 15;
    const int quad = lane >> 4;
    const int rowbase = wave * 32;            // 2 row-tiles per wave

    if (t == 0) blkcnt = 0;

    // ---- stage z -> LDS (8 float4/thread, register transpose, b128 writes) ----
    {
        const int hwl   = (t & 31) * 4;       // 4 consecutive rows
        const int dbase = (t >> 5) * 8;       // 8 consecutive d
        float4 v[8];
        #pragma unroll
        for (int p = 0; p < 8; ++p)
            v[p] = *(const float4*)(z + (size_t)b * DHW + (size_t)(dbase + p) * HW + hw0 + hwl);
        #pragma unroll
        for (int c = 0; c < 4; ++c) {
            short8 hi, lo;
            #pragma unroll
            for (int p = 0; p < 8; ++p) {
                const float* vp = (const float*)&v[p];
                float f = -2.0f * vp[c];
                unsigned short hh = f32_to_bf16_rne(f);
                unsigned short ll = f32_to_bf16_rne(f - bf16_to_f32(hh));
                hi[p] = (short)hh; lo[p] = (short)ll;
            }
            *(short8*)&zh[(hwl + c) * PITCH + dbase] = hi;
            *(short8*)&zl[(hwl + c) * PITCH + dbase] = lo;
        }
    }

    // ---- stage norms -> LDS ----
    #pragma unroll
    for (int j = 0; j < 4; ++j) nsh[t + j * 256] = norms[t + j * 256];

    // ---- B-staging prologue: thread owns 32 B hi + 32 B lo per chunk ----
    const int cc = t >> 2;                    // code within chunk (0..63)
    const int pp = (t & 3) * 16;              // short offset within code row
    short8 pf0[4], pf1[4];                    // [0..1]=hi, [2..3]=lo
    #pragma unroll
    for (int j = 0; j < 2; ++j) {
        pf0[j]     = *(const short8*)(ehg + (size_t)cc * DIM + pp + j * 8);
        pf0[2 + j] = *(const short8*)(elg + (size_t)cc * DIM + pp + j * 8);
        pf1[j]     = *(const short8*)(ehg + (size_t)(BCHUNK + cc) * DIM + pp + j * 8);
        pf1[2 + j] = *(const short8*)(elg + (size_t)(BCHUNK + cc) * DIM + pp + j * 8);
    }
    __syncthreads();                          // z + norms ready (prologue loads drain once)

    // ---- A-fragments (32 VGPRs, resident) ----
    short8 a_h[2][2], a_l[2][2];
    #pragma unroll
    for (int rt = 0; rt < 2; ++rt)
        #pragma unroll
        for (int kt = 0; kt < 2; ++kt) {
            const int idx = (rowbase + rt * 16 + l15) * PITCH + kt * 32 + quad * 8;
            a_h[rt][kt] = *(const short8*)&zh[idx];
            a_l[rt][kt] = *(const short8*)&zl[idx];
        }

    // ---- write chunk 0 into buf0 ----
    #pragma unroll
    for (int j = 0; j < 2; ++j) {
        *(short8*)&ebh0[cc * PITCH + pp + j * 8] = pf0[j];
        *(short8*)&ebl0[cc * PITCH + pp + j * 8] = pf0[2 + j];
    }
    __syncthreads();                          // buf0 ready

    float best[2][4], best2[2][4];
    #pragma unroll
    for (int rt = 0; rt < 2; ++rt)
        #pragma unroll
        for (int r = 0; r < 4; ++r) { best[rt][r] = 3.0e38f; best2[rt][r] = 3.0e38f; }

    // chunk body: issue ch+2 loads -> pfL; compute chunk ch from (bhR,blR);
    // write pfW (chunk ch+1) -> (bhW,blW); barrier.
    auto body = [&](int ch, const short* bhR, const short* blR,
                    short* bhW, short* blW, short8 (&pfL)[4], short8 (&pfW)[4]) {
        if (ch + 2 < NBCHUNK) {
            const size_t gb = (size_t)((ch + 2) * BCHUNK + cc) * DIM + pp;
            #pragma unroll
            for (int j = 0; j < 2; ++j) {
                pfL[j]     = *(const short8*)(ehg + gb + j * 8);
                pfL[2 + j] = *(const short8*)(elg + gb + j * 8);
            }
        }
        // hoist the 4 norm reads (they gate each MFMA chain's acc init)
        float nrm4[4];
        #pragma unroll
        for (int ct = 0; ct < 4; ++ct) nrm4[ct] = nsh[ch * BCHUNK + ct * 16 + l15];

        #pragma unroll
        for (int ct = 0; ct < 4; ++ct) {
            const int crow = ct * 16 + l15;
            short8 Bh0 = *(const short8*)&bhR[crow * PITCH + quad * 8];
            short8 Bh1 = *(const short8*)&bhR[crow * PITCH + 32 + quad * 8];
            short8 Bl0 = *(const short8*)&blR[crow * PITCH + quad * 8];
            short8 Bl1 = *(const short8*)&blR[crow * PITCH + 32 + quad * 8];
            const unsigned colbits = (unsigned)(ch * BCHUNK + crow);
            const float nrm = nrm4[ct];
            #pragma unroll
            for (int rt = 0; rt < 2; ++rt) {
                f32x4 acc = { nrm, nrm, nrm, nrm };
                acc = __builtin_amdgcn_mfma_f32_16x16x32_bf16(a_h[rt][0], Bh0, acc, 0, 0, 0);
                acc = __builtin_amdgcn_mfma_f32_16x16x32_bf16(a_h[rt][1], Bh1, acc, 0, 0, 0);
                acc = __builtin_amdgcn_mfma_f32_16x16x32_bf16(a_h[rt][0], Bl0, acc, 0, 0, 0);
                acc = __builtin_amdgcn_mfma_f32_16x16x32_bf16(a_h[rt][1], Bl1, acc, 0, 0, 0);
                acc = __builtin_amdgcn_mfma_f32_16x16x32_bf16(a_l[rt][0], Bh0, acc, 0, 0, 0);
                acc = __builtin_amdgcn_mfma_f32_16x16x32_bf16(a_l[rt][1], Bh1, acc, 0, 0, 0);
                #pragma unroll
                for (int r = 0; r < 4; ++r) {
                    float p = __uint_as_float((__float_as_uint(acc[r]) & 0xFFFFFC00u) | colbits);
                    best2[rt][r] = fminf(best2[rt][r], fmaxf(best[rt][r], p));
                    best[rt][r]  = fminf(best[rt][r], p);
                }
            }
        }
        if (ch + 1 < NBCHUNK) {
            #pragma unroll
            for (int j = 0; j < 2; ++j) {
                *(short8*)&bhW[cc * PITCH + pp + j * 8] = pfW[j];
                *(short8*)&blW[cc * PITCH + pp + j * 8] = pfW[2 + j];
            }
        }
        __syncthreads();
    };

    for (int chp = 0; chp < 8; ++chp) {
        body(2 * chp,     ebh0, ebl0, ebh1, ebl1, pf0, pf1);
        body(2 * chp + 1, ebh1, ebl1, ebh0, ebl0, pf1, pf0);
    }

    // ---- merge across 16 code-lanes; each wave has complete top-2 for its rows ----
    #pragma unroll
    for (int rt = 0; rt < 2; ++rt)
        #pragma unroll
        for (int r = 0; r < 4; ++r) {
            float bb = best[rt][r], b2 = best2[rt][r];
            #pragma unroll
            for (int m = 1; m <= 8; m <<= 1) {
                float ob  = __shfl_xor(bb, m, 64);
                float ob2 = __shfl_xor(b2, m, 64);
                b2 = fminf(fminf(b2, ob2), fmaxf(bb, ob));
                bb = fminf(bb, ob);
            }
            best[rt][r] = bb; best2[rt][r] = b2;
        }

    // ---- per-row result: flags into LDS list (LDS atomics only) ----
    if (l15 == 0) {
        #pragma unroll
        for (int rt = 0; rt < 2; ++rt)
            #pragma unroll
            for (int r = 0; r < 4; ++r) {
                unsigned ub = __float_as_uint(best[rt][r]);
                int k = (int)(ub & 1023u);
                float sb  = __uint_as_float(ub & 0xFFFFFC00u);
                float sb2 = __uint_as_float(__float_as_uint(best2[rt][r]) & 0xFFFFFC00u);
                int rowl = rowbase + rt * 16 + quad * 4 + r;
                int flag = 0;
                if (sb2 - sb < EPS) {
                    int p = atomicAdd(&blkcnt, 1);   // LDS atomic, per-CU fast
                    blkrows[p] = rowl; flag = 1;
                }
                kidx[rowl] = k | (flag << 15);
            }
    }
    __syncthreads();
    // ---- ONE global atomic per block reserves the slot range ----
    if (t == 0) blkbase = (blkcnt > 0) ? atomicAdd(counter, blkcnt) : 0;
    __syncthreads();
    if (t < blkcnt) {
        const int rowl = blkrows[t];
        const int slot = blkbase + t;
        if (slot < cap) worklist[slot] = n0 + rowl;
        else            kidx[rowl] &= 0x7FFF;   // overflow: un-flag, epilogue handles
    }
    __syncthreads();

    // ---- epilogue: row = t&127, dgrp = t>>7 covers 32 d; coalesced stores ----
    float lsum = 0.f;
    {
        const int row  = t & 127;
        const int d0   = (t >> 7) * 32;
        const int ki   = kidx[row];
        const int k    = ki & 1023;
        const int flag = (ki >> 15) & 1;
        if (!flag) {
            const float4* cbr = (const float4*)(cb + k * DIM + d0);
            const short8* zhr = (const short8*)&zh[row * PITCH + d0];
            const short8* zlr = (const short8*)&zl[row * PITCH + d0];
            float* op = out + (size_t)b * DHW + (size_t)d0 * HW + hw0 + row;
            #pragma unroll
            for (int g = 0; g < 4; ++g) {
                short8 hh = zhr[g];
                short8 ll = zlr[g];
                float4 e0 = cbr[2 * g];
                float4 e1 = cbr[2 * g + 1];
                const float ev[8] = { e0.x, e0.y, e0.z, e0.w, e1.x, e1.y, e1.z, e1.w };
                #pragma unroll
                for (int j = 0; j < 8; ++j) {
                    float zv = -0.5f * (bf16_to_f32((unsigned short)hh[j]) +
                                        bf16_to_f32((unsigned short)ll[j]));
                    op[(size_t)(g * 8 + j) * HW] = ev[j];
                    float df = ev[j] - zv;
                    lsum = fmaf(df, df, lsum);
                }
            }
        }
    }
    #pragma unroll
    for (int off = 32; off > 0; off >>= 1) lsum += __shfl_down(lsum, off, 64);
    if (lane == 0) wsum[wave] = lsum;
    __syncthreads();
    if (t == 0)
        atomicAdd(loss_acc, (double)((wsum[0] + wsum[1]) + (wsum[2] + wsum[3])));
}

// Rescue v3: 8 flagged vectors per block (2 per wave), codebook staged once per
// block-iteration (4 chunks). f64 dot-form distance (||c||^2 - 2 z.c). Loss
// contributions block-reduced through LDS -> ONE f64 atomicAdd per
// block-iteration (fixed the per-vector same-address f64 RMW convoy).
__global__ __launch_bounds__(256, 2) void vq_rescue(
    const float* __restrict__ z, const float* __restrict__ cb,
    float* __restrict__ out, double* __restrict__ loss_acc,
    const int* __restrict__ counter, const int* __restrict__ worklist, int cap,
    int* __restrict__ done, float* __restrict__ loss_out)
{
    __shared__ float  cbs[CHUNK_ROWS * CPITCH];  // 66.5 KiB (one chunk)
    __shared__ float  zsh[RB_BLK][DIM];          // 2 KiB (per-wave private rows)
    __shared__ double dsum[4];

    int count = *counter; if (count > cap) count = cap;
    const int t    = threadIdx.x;
    const int wave = t >> 6;
    const int lane = t & 63;

    for (int base = blockIdx.x * RB_BLK; base < count; base += gridDim.x * RB_BLK) {
        int    nrow[RB_VEC];
        bool   act[RB_VEC];
        float  zval[RB_VEC];
        double znorm[RB_VEC];

        // issue all z-row loads up front (latency hides under chunk-0 staging)
        #pragma unroll
        for (int v = 0; v < RB_VEC; ++v) {
            const int i = base + wave * RB_VEC + v;
            act[v] = (i < count);
            nrow[v] = 0;
            zval[v] = 0.f;
            if (act[v]) {
                nrow[v] = worklist[i];
                const int bb = nrow[v] >> 12, hw = nrow[v] & 4095;
                zval[v] = z[(size_t)bb * DHW + (size_t)lane * HW + hw];
            }
        }
        #pragma unroll
        for (int v = 0; v < RB_VEC; ++v) {
            zsh[wave * RB_VEC + v][lane] = zval[v];
            double zn = (double)zval[v] * (double)zval[v];
            #pragma unroll
            for (int m = 1; m <= 32; m <<= 1) zn += __shfl_xor(zn, m, 64);
            znorm[v] = zn;
        }

        double bestd[RB_VEC]; int bestk[RB_VEC];
        #pragma unroll
        for (int v = 0; v < RB_VEC; ++v) { bestd[v] = 1.0e300; bestk[v] = 0; }

        for (int chunk = 0; chunk < 4; ++chunk) {
            __syncthreads();                 // previous chunk's readers done
            const float4* src = (const float4*)(cb + (size_t)chunk * CHUNK_ROWS * DIM);
            #pragma unroll
            for (int ii = 0; ii < 16; ++ii) {
                const int f = t + ii * 256;
                float4 v4 = src[f];
                float* dst = &cbs[(f >> 4) * CPITCH + (f & 15) * 4];
                dst[0] = v4.x; dst[1] = v4.y; dst[2] = v4.z; dst[3] = v4.w;
            }
            __syncthreads();                 // chunk visible

            double nj[4];                    // ||c_row||^2, f64, per j
            double dot[4][RB_VEC];           // z.c per (row, vector)
            #pragma unroll
            for (int j = 0; j < 4; ++j) {
                nj[j] = 0.0;
                #pragma unroll
                for (int v = 0; v < RB_VEC; ++v) dot[j][v] = 0.0;
            }
            #pragma unroll
            for (int dblk = 0; dblk < 8; ++dblk) {
                float zb[RB_VEC][8];
                #pragma unroll
                for (int v = 0; v < RB_VEC; ++v)
                    #pragma unroll
                    for (int dd = 0; dd < 8; ++dd)
                        zb[v][dd] = zsh[wave * RB_VEC + v][dblk * 8 + dd];
                #pragma unroll
                for (int j = 0; j < 4; ++j) {
                    const float* cr = &cbs[(j * 64 + lane) * CPITCH + dblk * 8];
                    float cv[8];
                    #pragma unroll
                    for (int dd = 0; dd < 8; ++dd) cv[dd] = cr[dd];
                    #pragma unroll
                    for (int dd = 0; dd < 8; ++dd)
                        nj[j] = fma((double)cv[dd], (double)cv[dd], nj[j]);
                    #pragma unroll
                    for (int v = 0; v < RB_VEC; ++v)
                        #pragma unroll
                        for (int dd = 0; dd < 8; ++dd)
                            dot[j][v] = fma((double)cv[dd], (double)zb[v][dd], dot[j][v]);
                }
            }
            #pragma unroll
            for (int j = 0; j < 4; ++j) {
                const int gk = chunk * CHUNK_ROWS + j * 64 + lane;
                #pragma unroll
                for (int v = 0; v < RB_VEC; ++v) {
                    double d2 = fma(-2.0, dot[j][v], nj[j]);   // ||c||^2 - 2 z.c
                    if (d2 < bestd[v]) { bestd[v] = d2; bestk[v] = gk; }
                }
            }
        }

        double lloss = 0.0;                  // lane0-of-wave partial loss
        #pragma unroll
        for (int v = 0; v < RB_VEC; ++v) {
            double bd = bestd[v]; int bk = bestk[v];
            #pragma unroll
            for (int m = 1; m <= 32; m <<= 1) {
                double od = __shfl_xor(bd, m, 64);
                int    ok = __shfl_xor(bk, m, 64);
                if (od < bd || (od == bd && ok < bk)) { bd = od; bk = ok; }
            }
            if (act[v]) {
                const int bb = nrow[v] >> 12, hw = nrow[v] & 4095;
                out[(size_t)bb * DHW + (size_t)lane * HW + hw] = cb[bk * DIM + lane];
                if (lane == 0) lloss += bd + znorm[v];
            }
        }
        // block-reduce loss -> single f64 atomic per block-iteration
        if (lane == 0) dsum[wave] = lloss;
        __syncthreads();
        if (t == 0) {
            double s = (dsum[0] + dsum[1]) + (dsum[2] + dsum[3]);
            if (s != 0.0) atomicAdd(loss_acc, s);
        }
    }

    __threadfence();
    __shared__ int ticket_s;
    if (t == 0) ticket_s = atomicAdd(done, 1);
    __syncthreads();
    if (t == 0 && ticket_s == (int)gridDim.x - 1) {
        double total = atomicAdd(loss_acc, 0.0);
        *loss_out = (float)(1.25 * total * (1.0 / (double)((long)N_VEC * DIM)));
    }
}

extern "C" void kernel_launch(void* const* d_in, const int* in_sizes, int n_in,
                              void* d_out, int out_size, void* d_ws, size_t ws_size,
                              hipStream_t stream) {
    const float* z  = (const float*)d_in[0];
    const float* cb = (const float*)d_in[1];
    float* out      = (float*)d_out;
    char*  ws       = (char*)d_ws;

    double* loss_acc = (double*)ws;
    int*    counter  = (int*)(ws + 8);
    int*    done     = (int*)(ws + 12);
    float*  norms    = (float*)(ws + 64);
    short*  ehg      = (short*)(ws + 8192);
    short*  elg      = (short*)(ws + 139264);
    int*    worklist = (int*)(ws + 270336);

    int cap = WLCAP;
    long avail = ((long)ws_size - 270336) / 4;
    if (avail < cap) cap = (avail > 0) ? (int)avail : 0;

    vq_prep<<<dim3(KCODE / 16), dim3(256), 0, stream>>>(
        cb, norms, ehg, elg, loss_acc, counter, done);
    vq_main<<<dim3(N_VEC / BLK_ROWS), dim3(256), 0, stream>>>(
        z, cb, norms, ehg, elg, out, loss_acc, counter, worklist, cap);
    vq_rescue<<<dim3(512), dim3(256), 0, stream>>>(
        z, cb, out, loss_acc, counter, worklist, cap, done, out + (out_size - 1));
}

// Round 6
// 227.970 us; speedup vs baseline: 1.4606x; 1.0106x over previous
//
#include <hip/hip_runtime.h>

#define N_VEC 131072   // B*H*W
#define DIM   64
#define KCODE 1024
#define HW    4096
#define DHW   262144
#define EPS   0.125f   // near-tie margin (validated r4-r8)
#define WLCAP 32768
#define BLK_ROWS 128   // rows per block; 4 waves x 32 rows
#define PITCH 72       // shorts per LDS row (144 B)
#define BCHUNK 64      // main: codes per LDS-staged codebook chunk
#define NBCHUNK 16
#define CPITCH 68      // rescue LDS pitch: 272 B stride = 16 mod 128 -> conflict-free b128
#define CHUNK_ROWS 256
#define RB_VEC 2       // rescue: vectors per wave
#define RB_BLK 8       // rescue: vectors per block (4 waves x 2)

typedef short short8 __attribute__((ext_vector_type(8)));
typedef float f32x4  __attribute__((ext_vector_type(4)));

// ws layout (bytes):
//   0      : double loss accumulator
//   8      : int flagged counter
//   12     : int done-ticket counter
//   64     : norms f32[1024]
//   8192   : eh  bf16-bits short[65536]
//   139264 : el  bf16-bits short[65536]
//   270336 : worklist int[WLCAP]

__device__ __forceinline__ unsigned short f32_to_bf16_rne(float x) {
    unsigned u = __float_as_uint(x);
    u += 0x7FFFu + ((u >> 16) & 1u);
    return (unsigned short)(u >> 16);
}
__device__ __forceinline__ float bf16_to_f32(unsigned short h) {
    return __uint_as_float((unsigned)h << 16);
}

__global__ __launch_bounds__(256) void vq_prep(
    const float* __restrict__ cb, float* __restrict__ norms,
    short* __restrict__ ehg, short* __restrict__ elg,
    double* __restrict__ loss_acc, int* __restrict__ counter,
    int* __restrict__ done)
{
    const int t = threadIdx.x;
    if (blockIdx.x == 0 && t == 0) { *loss_acc = 0.0; *counter = 0; *done = 0; }

    const int k    = blockIdx.x * 16 + (t >> 4);
    const int part = t & 15;
    const float4 v = *(const float4*)(cb + k * DIM + part * 4);

    float s = 0.f;
    s = fmaf(v.x, v.x, s); s = fmaf(v.y, v.y, s);
    s = fmaf(v.z, v.z, s); s = fmaf(v.w, v.w, s);
    #pragma unroll
    for (int m = 1; m <= 8; m <<= 1) s += __shfl_xor(s, m, 64);
    if (part == 0) norms[k] = s;

    short h[4], l[4];
    const float vv[4] = { v.x, v.y, v.z, v.w };
    #pragma unroll
    for (int j = 0; j < 4; ++j) {
        unsigned short hh = f32_to_bf16_rne(vv[j]);
        unsigned short ll = f32_to_bf16_rne(vv[j] - bf16_to_f32(hh));
        h[j] = (short)hh; l[j] = (short)ll;
    }
    *(short4*)(ehg + k * DIM + part * 4) = make_short4(h[0], h[1], h[2], h[3]);
    *(short4*)(elg + k * DIM + part * 4) = make_short4(l[0], l[1], l[2], l[3]);
}

// Main v6 (unchanged from R5): LDS-staged B double-buffered, per-block LDS
// aggregation of worklist slots -> ONE global atomicAdd per block.
__global__ __launch_bounds__(256, 2) void vq_main(
    const float* __restrict__ z, const float* __restrict__ cb,
    const float* __restrict__ norms, const short* __restrict__ ehg,
    const short* __restrict__ elg, float* __restrict__ out,
    double* __restrict__ loss_acc, int* __restrict__ counter,
    int* __restrict__ worklist, int cap)
{
    __shared__ short  zh[BLK_ROWS * PITCH];   // hi(-2z) bf16 bits, [row=hw][d]
    __shared__ short  zl[BLK_ROWS * PITCH];
    __shared__ short  ebh0[BCHUNK * PITCH];   // codebook chunk hi, double-buffered
    __shared__ short  ebh1[BCHUNK * PITCH];
    __shared__ short  ebl0[BCHUNK * PITCH];
    __shared__ short  ebl1[BCHUNK * PITCH];
    __shared__ float  nsh[KCODE];             // norms, block-resident
    __shared__ int    kidx[BLK_ROWS];
    __shared__ float  wsum[4];
    __shared__ int    blkrows[BLK_ROWS];      // flagged row-local ids
    __shared__ int    blkcnt;
    __shared__ int    blkbase;

    const int t   = threadIdx.x;              // 0..255
    const int n0  = blockIdx.x * BLK_ROWS;
    const int b   = n0 >> 12;
    const int hw0 = n0 & 4095;

    const int lane = t & 63;
    const int wave = t >> 6;                  // 0..3
    const int l15  = lane & 15;
    const int quad = lane >> 4;
    const int rowbase = wave * 32;            // 2 row-tiles per wave

    if (t == 0) blkcnt = 0;

    // ---- stage z -> LDS (8 float4/thread, register transpose, b128 writes) ----
    {
        const int hwl   = (t & 31) * 4;       // 4 consecutive rows
        const int dbase = (t >> 5) * 8;       // 8 consecutive d
        float4 v[8];
        #pragma unroll
        for (int p = 0; p < 8; ++p)
            v[p] = *(const float4*)(z + (size_t)b * DHW + (size_t)(dbase + p) * HW + hw0 + hwl);
        #pragma unroll
        for (int c = 0; c < 4; ++c) {
            short8 hi, lo;
            #pragma unroll
            for (int p = 0; p < 8; ++p) {
                const float* vp = (const float*)&v[p];
                float f = -2.0f * vp[c];
                unsigned short hh = f32_to_bf16_rne(f);
                unsigned short ll = f32_to_bf16_rne(f - bf16_to_f32(hh));
                hi[p] = (short)hh; lo[p] = (short)ll;
            }
            *(short8*)&zh[(hwl + c) * PITCH + dbase] = hi;
            *(short8*)&zl[(hwl + c) * PITCH + dbase] = lo;
        }
    }

    // ---- stage norms -> LDS ----
    #pragma unroll
    for (int j = 0; j < 4; ++j) nsh[t + j * 256] = norms[t + j * 256];

    // ---- B-staging prologue: thread owns 32 B hi + 32 B lo per chunk ----
    const int cc = t >> 2;                    // code within chunk (0..63)
    const int pp = (t & 3) * 16;              // short offset within code row
    short8 pf0[4], pf1[4];                    // [0..1]=hi, [2..3]=lo
    #pragma unroll
    for (int j = 0; j < 2; ++j) {
        pf0[j]     = *(const short8*)(ehg + (size_t)cc * DIM + pp + j * 8);
        pf0[2 + j] = *(const short8*)(elg + (size_t)cc * DIM + pp + j * 8);
        pf1[j]     = *(const short8*)(ehg + (size_t)(BCHUNK + cc) * DIM + pp + j * 8);
        pf1[2 + j] = *(const short8*)(elg + (size_t)(BCHUNK + cc) * DIM + pp + j * 8);
    }
    __syncthreads();                          // z + norms ready (prologue loads drain once)

    // ---- A-fragments (32 VGPRs, resident) ----
    short8 a_h[2][2], a_l[2][2];
    #pragma unroll
    for (int rt = 0; rt < 2; ++rt)
        #pragma unroll
        for (int kt = 0; kt < 2; ++kt) {
            const int idx = (rowbase + rt * 16 + l15) * PITCH + kt * 32 + quad * 8;
            a_h[rt][kt] = *(const short8*)&zh[idx];
            a_l[rt][kt] = *(const short8*)&zl[idx];
        }

    // ---- write chunk 0 into buf0 ----
    #pragma unroll
    for (int j = 0; j < 2; ++j) {
        *(short8*)&ebh0[cc * PITCH + pp + j * 8] = pf0[j];
        *(short8*)&ebl0[cc * PITCH + pp + j * 8] = pf0[2 + j];
    }
    __syncthreads();                          // buf0 ready

    float best[2][4], best2[2][4];
    #pragma unroll
    for (int rt = 0; rt < 2; ++rt)
        #pragma unroll
        for (int r = 0; r < 4; ++r) { best[rt][r] = 3.0e38f; best2[rt][r] = 3.0e38f; }

    // chunk body: issue ch+2 loads -> pfL; compute chunk ch from (bhR,blR);
    // write pfW (chunk ch+1) -> (bhW,blW); barrier.
    auto body = [&](int ch, const short* bhR, const short* blR,
                    short* bhW, short* blW, short8 (&pfL)[4], short8 (&pfW)[4]) {
        if (ch + 2 < NBCHUNK) {
            const size_t gb = (size_t)((ch + 2) * BCHUNK + cc) * DIM + pp;
            #pragma unroll
            for (int j = 0; j < 2; ++j) {
                pfL[j]     = *(const short8*)(ehg + gb + j * 8);
                pfL[2 + j] = *(const short8*)(elg + gb + j * 8);
            }
        }
        // hoist the 4 norm reads (they gate each MFMA chain's acc init)
        float nrm4[4];
        #pragma unroll
        for (int ct = 0; ct < 4; ++ct) nrm4[ct] = nsh[ch * BCHUNK + ct * 16 + l15];

        #pragma unroll
        for (int ct = 0; ct < 4; ++ct) {
            const int crow = ct * 16 + l15;
            short8 Bh0 = *(const short8*)&bhR[crow * PITCH + quad * 8];
            short8 Bh1 = *(const short8*)&bhR[crow * PITCH + 32 + quad * 8];
            short8 Bl0 = *(const short8*)&blR[crow * PITCH + quad * 8];
            short8 Bl1 = *(const short8*)&blR[crow * PITCH + 32 + quad * 8];
            const unsigned colbits = (unsigned)(ch * BCHUNK + crow);
            const float nrm = nrm4[ct];
            #pragma unroll
            for (int rt = 0; rt < 2; ++rt) {
                f32x4 acc = { nrm, nrm, nrm, nrm };
                acc = __builtin_amdgcn_mfma_f32_16x16x32_bf16(a_h[rt][0], Bh0, acc, 0, 0, 0);
                acc = __builtin_amdgcn_mfma_f32_16x16x32_bf16(a_h[rt][1], Bh1, acc, 0, 0, 0);
                acc = __builtin_amdgcn_mfma_f32_16x16x32_bf16(a_h[rt][0], Bl0, acc, 0, 0, 0);
                acc = __builtin_amdgcn_mfma_f32_16x16x32_bf16(a_h[rt][1], Bl1, acc, 0, 0, 0);
                acc = __builtin_amdgcn_mfma_f32_16x16x32_bf16(a_l[rt][0], Bh0, acc, 0, 0, 0);
                acc = __builtin_amdgcn_mfma_f32_16x16x32_bf16(a_l[rt][1], Bh1, acc, 0, 0, 0);
                #pragma unroll
                for (int r = 0; r < 4; ++r) {
                    float p = __uint_as_float((__float_as_uint(acc[r]) & 0xFFFFFC00u) | colbits);
                    best2[rt][r] = fminf(best2[rt][r], fmaxf(best[rt][r], p));
                    best[rt][r]  = fminf(best[rt][r], p);
                }
            }
        }
        if (ch + 1 < NBCHUNK) {
            #pragma unroll
            for (int j = 0; j < 2; ++j) {
                *(short8*)&bhW[cc * PITCH + pp + j * 8] = pfW[j];
                *(short8*)&blW[cc * PITCH + pp + j * 8] = pfW[2 + j];
            }
        }
        __syncthreads();
    };

    for (int chp = 0; chp < 8; ++chp) {
        body(2 * chp,     ebh0, ebl0, ebh1, ebl1, pf0, pf1);
        body(2 * chp + 1, ebh1, ebl1, ebh0, ebl0, pf1, pf0);
    }

    // ---- merge across 16 code-lanes; each wave has complete top-2 for its rows ----
    #pragma unroll
    for (int rt = 0; rt < 2; ++rt)
        #pragma unroll
        for (int r = 0; r < 4; ++r) {
            float bb = best[rt][r], b2 = best2[rt][r];
            #pragma unroll
            for (int m = 1; m <= 8; m <<= 1) {
                float ob  = __shfl_xor(bb, m, 64);
                float ob2 = __shfl_xor(b2, m, 64);
                b2 = fminf(fminf(b2, ob2), fmaxf(bb, ob));
                bb = fminf(bb, ob);
            }
            best[rt][r] = bb; best2[rt][r] = b2;
        }

    // ---- per-row result: flags into LDS list (LDS atomics only) ----
    if (l15 == 0) {
        #pragma unroll
        for (int rt = 0; rt < 2; ++rt)
            #pragma unroll
            for (int r = 0; r < 4; ++r) {
                unsigned ub = __float_as_uint(best[rt][r]);
                int k = (int)(ub & 1023u);
                float sb  = __uint_as_float(ub & 0xFFFFFC00u);
                float sb2 = __uint_as_float(__float_as_uint(best2[rt][r]) & 0xFFFFFC00u);
                int rowl = rowbase + rt * 16 + quad * 4 + r;
                int flag = 0;
                if (sb2 - sb < EPS) {
                    int p = atomicAdd(&blkcnt, 1);   // LDS atomic, per-CU fast
                    blkrows[p] = rowl; flag = 1;
                }
                kidx[rowl] = k | (flag << 15);
            }
    }
    __syncthreads();
    // ---- ONE global atomic per block reserves the slot range ----
    if (t == 0) blkbase = (blkcnt > 0) ? atomicAdd(counter, blkcnt) : 0;
    __syncthreads();
    if (t < blkcnt) {
        const int rowl = blkrows[t];
        const int slot = blkbase + t;
        if (slot < cap) worklist[slot] = n0 + rowl;
        else            kidx[rowl] &= 0x7FFF;   // overflow: un-flag, epilogue handles
    }
    __syncthreads();

    // ---- epilogue: row = t&127, dgrp = t>>7 covers 32 d; coalesced stores ----
    float lsum = 0.f;
    {
        const int row  = t & 127;
        const int d0   = (t >> 7) * 32;
        const int ki   = kidx[row];
        const int k    = ki & 1023;
        const int flag = (ki >> 15) & 1;
        if (!flag) {
            const float4* cbr = (const float4*)(cb + k * DIM + d0);
            const short8* zhr = (const short8*)&zh[row * PITCH + d0];
            const short8* zlr = (const short8*)&zl[row * PITCH + d0];
            float* op = out + (size_t)b * DHW + (size_t)d0 * HW + hw0 + row;
            #pragma unroll
            for (int g = 0; g < 4; ++g) {
                short8 hh = zhr[g];
                short8 ll = zlr[g];
                float4 e0 = cbr[2 * g];
                float4 e1 = cbr[2 * g + 1];
                const float ev[8] = { e0.x, e0.y, e0.z, e0.w, e1.x, e1.y, e1.z, e1.w };
                #pragma unroll
                for (int j = 0; j < 8; ++j) {
                    float zv = -0.5f * (bf16_to_f32((unsigned short)hh[j]) +
                                        bf16_to_f32((unsigned short)ll[j]));
                    op[(size_t)(g * 8 + j) * HW] = ev[j];
                    float df = ev[j] - zv;
                    lsum = fmaf(df, df, lsum);
                }
            }
        }
    }
    #pragma unroll
    for (int off = 32; off > 0; off >>= 1) lsum += __shfl_down(lsum, off, 64);
    if (lane == 0) wsum[wave] = lsum;
    __syncthreads();
    if (t == 0)
        atomicAdd(loss_acc, (double)((wsum[0] + wsum[1]) + (wsum[2] + wsum[3])));
}

// Rescue v4: same structure as v3 (8 vectors/block, block-reduced loss atomic)
// but ALL LDS traffic vectorized to float4. R1/R5 scaling showed wall time
// proportional to scalar-LDS-instruction count at ~120 cy each (exposed
// single-outstanding ds_read latency; 2 waves/SIMD can't hide it).
// CPITCH=68: row stride 272 B = 16 mod 128 -> each 8-lane group's 16 B
// chunks tile all 32 banks -> conflict-free ds_read_b128. LDS insts/iter:
// ~1792 scalar -> ~448 vector. f64 FMA order/values unchanged (bitwise-
// identical distances).
__global__ __launch_bounds__(256, 2) void vq_rescue(
    const float* __restrict__ z, const float* __restrict__ cb,
    float* __restrict__ out, double* __restrict__ loss_acc,
    const int* __restrict__ counter, const int* __restrict__ worklist, int cap,
    int* __restrict__ done, float* __restrict__ loss_out)
{
    __shared__ float  cbs[CHUNK_ROWS * CPITCH];  // 69.6 KiB (one chunk)
    __shared__ float  zsh[RB_BLK][DIM];          // 2 KiB (per-wave private rows)
    __shared__ double dsum[4];

    int count = *counter; if (count > cap) count = cap;
    const int t    = threadIdx.x;
    const int wave = t >> 6;
    const int lane = t & 63;

    for (int base = blockIdx.x * RB_BLK; base < count; base += gridDim.x * RB_BLK) {
        int    nrow[RB_VEC];
        bool   act[RB_VEC];
        float  zval[RB_VEC];
        double znorm[RB_VEC];

        // issue all z-row loads up front (latency hides under chunk-0 staging)
        #pragma unroll
        for (int v = 0; v < RB_VEC; ++v) {
            const int i = base + wave * RB_VEC + v;
            act[v] = (i < count);
            nrow[v] = 0;
            zval[v] = 0.f;
            if (act[v]) {
                nrow[v] = worklist[i];
                const int bb = nrow[v] >> 12, hw = nrow[v] & 4095;
                zval[v] = z[(size_t)bb * DHW + (size_t)lane * HW + hw];
            }
        }
        #pragma unroll
        for (int v = 0; v < RB_VEC; ++v) {
            zsh[wave * RB_VEC + v][lane] = zval[v];
            double zn = (double)zval[v] * (double)zval[v];
            #pragma unroll
            for (int m = 1; m <= 32; m <<= 1) zn += __shfl_xor(zn, m, 64);
            znorm[v] = zn;
        }

        double bestd[RB_VEC]; int bestk[RB_VEC];
        #pragma unroll
        for (int v = 0; v < RB_VEC; ++v) { bestd[v] = 1.0e300; bestk[v] = 0; }

        for (int chunk = 0; chunk < 4; ++chunk) {
            __syncthreads();                 // previous chunk's readers done
            const float4* src = (const float4*)(cb + (size_t)chunk * CHUNK_ROWS * DIM);
            #pragma unroll
            for (int ii = 0; ii < 16; ++ii) {
                const int f = t + ii * 256;
                float4 v4 = src[f];
                *(float4*)&cbs[(f >> 4) * CPITCH + (f & 15) * 4] = v4;  // b128 write
            }
            __syncthreads();                 // chunk visible

            double nj[4];                    // ||c_row||^2, f64, per j
            double dot[4][RB_VEC];           // z.c per (row, vector)
            #pragma unroll
            for (int j = 0; j < 4; ++j) {
                nj[j] = 0.0;
                #pragma unroll
                for (int v = 0; v < RB_VEC; ++v) dot[j][v] = 0.0;
            }
            #pragma unroll
            for (int dblk = 0; dblk < 8; ++dblk) {
                float zb[RB_VEC][8];
                #pragma unroll
                for (int v = 0; v < RB_VEC; ++v) {
                    const float4* zr = (const float4*)&zsh[wave * RB_VEC + v][dblk * 8];
                    float4 z0 = zr[0], z1 = zr[1];       // b128 broadcast reads
                    zb[v][0] = z0.x; zb[v][1] = z0.y; zb[v][2] = z0.z; zb[v][3] = z0.w;
                    zb[v][4] = z1.x; zb[v][5] = z1.y; zb[v][6] = z1.z; zb[v][7] = z1.w;
                }
                #pragma unroll
                for (int j = 0; j < 4; ++j) {
                    const float4* cr = (const float4*)&cbs[(j * 64 + lane) * CPITCH + dblk * 8];
                    float4 c0 = cr[0], c1 = cr[1];       // b128 conflict-free reads
                    const float cv[8] = { c0.x, c0.y, c0.z, c0.w, c1.x, c1.y, c1.z, c1.w };
                    #pragma unroll
                    for (int dd = 0; dd < 8; ++dd)
                        nj[j] = fma((double)cv[dd], (double)cv[dd], nj[j]);
                    #pragma unroll
                    for (int v = 0; v < RB_VEC; ++v)
                        #pragma unroll
                        for (int dd = 0; dd < 8; ++dd)
                            dot[j][v] = fma((double)cv[dd], (double)zb[v][dd], dot[j][v]);
                }
            }
            #pragma unroll
            for (int j = 0; j < 4; ++j) {
                const int gk = chunk * CHUNK_ROWS + j * 64 + lane;
                #pragma unroll
                for (int v = 0; v < RB_VEC; ++v) {
                    double d2 = fma(-2.0, dot[j][v], nj[j]);   // ||c||^2 - 2 z.c
                    if (d2 < bestd[v]) { bestd[v] = d2; bestk[v] = gk; }
                }
            }
        }

        double lloss = 0.0;                  // lane0-of-wave partial loss
        #pragma unroll
        for (int v = 0; v < RB_VEC; ++v) {
            double bd = bestd[v]; int bk = bestk[v];
            #pragma unroll
            for (int m = 1; m <= 32; m <<= 1) {
                double od = __shfl_xor(bd, m, 64);
                int    ok = __shfl_xor(bk, m, 64);
                if (od < bd || (od == bd && ok < bk)) { bd = od; bk = ok; }
            }
            if (act[v]) {
                const int bb = nrow[v] >> 12, hw = nrow[v] & 4095;
                out[(size_t)bb * DHW + (size_t)lane * HW + hw] = cb[bk * DIM + lane];
                if (lane == 0) lloss += bd + znorm[v];
            }
        }
        // block-reduce loss -> single f64 atomic per block-iteration
        if (lane == 0) dsum[wave] = lloss;
        __syncthreads();
        if (t == 0) {
            double s = (dsum[0] + dsum[1]) + (dsum[2] + dsum[3]);
            if (s != 0.0) atomicAdd(loss_acc, s);
        }
    }

    __threadfence();
    __shared__ int ticket_s;
    if (t == 0) ticket_s = atomicAdd(done, 1);
    __syncthreads();
    if (t == 0 && ticket_s == (int)gridDim.x - 1) {
        double total = atomicAdd(loss_acc, 0.0);
        *loss_out = (float)(1.25 * total * (1.0 / (double)((long)N_VEC * DIM)));
    }
}

extern "C" void kernel_launch(void* const* d_in, const int* in_sizes, int n_in,
                              void* d_out, int out_size, void* d_ws, size_t ws_size,
                              hipStream_t stream) {
    const float* z  = (const float*)d_in[0];
    const float* cb = (const float*)d_in[1];
    float* out      = (float*)d_out;
    char*  ws       = (char*)d_ws;

    double* loss_acc = (double*)ws;
    int*    counter  = (int*)(ws + 8);
    int*    done     = (int*)(ws + 12);
    float*  norms    = (float*)(ws + 64);
    short*  ehg      = (short*)(ws + 8192);
    short*  elg      = (short*)(ws + 139264);
    int*    worklist = (int*)(ws + 270336);

    int cap = WLCAP;
    long avail = ((long)ws_size - 270336) / 4;
    if (avail < cap) cap = (avail > 0) ? (int)avail : 0;

    vq_prep<<<dim3(KCODE / 16), dim3(256), 0, stream>>>(
        cb, norms, ehg, elg, loss_acc, counter, done);
    vq_main<<<dim3(N_VEC / BLK_ROWS), dim3(256), 0, stream>>>(
        z, cb, norms, ehg, elg, out, loss_acc, counter, worklist, cap);
    vq_rescue<<<dim3(512), dim3(256), 0, stream>>>(
        z, cb, out, loss_acc, counter, worklist, cap, done, out + (out_size - 1));
}